// Round 14
// baseline (207.313 us; speedup 1.0000x reference)
//
#include <hip/hip_runtime.h>
#include <hip/hip_bf16.h>

typedef unsigned short u16;
typedef unsigned int u32;
typedef __attribute__((ext_vector_type(4))) unsigned short u16x4;
typedef __attribute__((ext_vector_type(8))) unsigned short u16x8;
typedef __attribute__((ext_vector_type(8))) __bf16 bf16x8;
typedef __attribute__((ext_vector_type(4))) float f32x4;

#define MFMA16(a, b, c) __builtin_amdgcn_mfma_f32_16x16x32_bf16(a, b, c, 0, 0, 0)

__device__ __forceinline__ u16 f2bf(float f){
  unsigned u = __builtin_bit_cast(unsigned, f);
  u += 0x7FFFu + ((u >> 16) & 1u);
  return (u16)(u >> 16);
}

__device__ __forceinline__ u32 cvtpk(float lo, float hi){
  u32 r;
  asm("v_cvt_pk_bf16_f32 %0, %1, %2" : "=v"(r) : "v"(lo), "v"(hi));
  return r;
}

__device__ __forceinline__ void load_lds16(const void* g, void* l){
  __builtin_amdgcn_global_load_lds((const __attribute__((address_space(1))) unsigned*)g,
                                   (__attribute__((address_space(3))) unsigned*)l, 16, 0, 0);
}

__device__ __forceinline__ void storeC(float* p, float v){ *p = v; }
__device__ __forceinline__ void storeC(u16* p, float v){ *p = f2bf(v); }

// ---------------- all 4 weight transposes in one launch ----------------
// Wq is additionally scaled by log2(e): scores then live in the exp2 domain.
__global__ __launch_bounds__(256) void transpose_all(const float* __restrict__ Wq,
                                                     const float* __restrict__ Wkv,
                                                     const float* __restrict__ Wout,
                                                     u16* __restrict__ WqT, u16* __restrict__ WkT,
                                                     u16* __restrict__ WvT, u16* __restrict__ WoT){
  const float* in; u16* out; int ldin;
  switch (blockIdx.z){
    case 0:  in = Wq;         out = WqT; ldin = 1024; break;
    case 1:  in = Wkv;        out = WkT; ldin = 2048; break;
    case 2:  in = Wkv + 1024; out = WvT; ldin = 2048; break;
    default: in = Wout;       out = WoT; ldin = 1024; break;
  }
  float scl = (blockIdx.z == 0) ? 1.44269504f : 1.0f;
  __shared__ float tile[64][65];
  int t = threadIdx.x;
  int tr = blockIdx.y * 64, tc = blockIdx.x * 64;
  int r0 = t >> 4, c0 = (t & 15) * 4;
#pragma unroll
  for (int i = 0; i < 4; ++i){
    int r = r0 + i * 16;
    const float4 val = *(const float4*)&in[(size_t)(tr + r) * ldin + tc + c0];
    tile[r][c0] = val.x; tile[r][c0+1] = val.y; tile[r][c0+2] = val.z; tile[r][c0+3] = val.w;
  }
  __syncthreads();
#pragma unroll
  for (int i = 0; i < 4; ++i){
    int n = r0 + i * 16;
    u16x4 o4;
    o4.x = f2bf(tile[c0+0][n] * scl); o4.y = f2bf(tile[c0+1][n] * scl);
    o4.z = f2bf(tile[c0+2][n] * scl); o4.w = f2bf(tile[c0+3][n] * scl);
    *(u16x4*)&out[(size_t)(tc + n) * 1024 + tr + c0] = o4;
  }
}

// ---------------- layernorm + bf16 cast, one row per block ----------------
__global__ __launch_bounds__(256) void ln_cast(const float* __restrict__ x, const float* __restrict__ xa,
                                               const float* __restrict__ w, const float* __restrict__ bb,
                                               u16* __restrict__ xn, u16* __restrict__ xan){
  int row = blockIdx.x;
  const float* src; u16* dst;
  if (row < 4096){ src = x + (size_t)row * 1024; dst = xn + (size_t)row * 1024; }
  else { src = xa + (size_t)(row - 4096) * 1024; dst = xan + (size_t)(row - 4096) * 1024; }
  int t = threadIdx.x;
  float4 v = ((const float4*)src)[t];
  float s = v.x + v.y + v.z + v.w;
  float ss = v.x*v.x + v.y*v.y + v.z*v.z + v.w*v.w;
#pragma unroll
  for (int o = 32; o > 0; o >>= 1){ s += __shfl_down(s, o); ss += __shfl_down(ss, o); }
  __shared__ float red[8];
  int wv = t >> 6;
  if ((t & 63) == 0){ red[wv] = s; red[wv + 4] = ss; }
  __syncthreads();
  if (t == 0){
    red[0] = red[0] + red[1] + red[2] + red[3];
    red[4] = red[4] + red[5] + red[6] + red[7];
  }
  __syncthreads();
  float mu = red[0] * (1.0f/1024.0f);
  float var = red[4] * (1.0f/1024.0f) - mu*mu;
  float rstd = rsqrtf(var + 1e-5f);
  float4 wv4 = ((const float4*)w)[t];
  float4 bv4 = ((const float4*)bb)[t];
  u16x4 o4;
  o4.x = f2bf((v.x - mu) * rstd * wv4.x + bv4.x);
  o4.y = f2bf((v.y - mu) * rstd * wv4.y + bv4.y);
  o4.z = f2bf((v.z - mu) * rstd * wv4.z + bv4.z);
  o4.w = f2bf((v.w - mu) * rstd * wv4.w + bv4.w);
  ((u16x4*)dst)[t] = o4;
}

// ---------------- BMx256 GEMM, 2-phase counted vmcnt (proven; used for out-GEMM) ----
template<int BM, int NQ, int TMASK, typename OutT>
__global__ __launch_bounds__(512, 2) void gemm256(
    const u16* __restrict__ A0, const u16* __restrict__ A1,
    const u16* __restrict__ A2, const u16* __restrict__ A3,
    const u16* __restrict__ B0, const u16* __restrict__ B1,
    const u16* __restrict__ B2, const u16* __restrict__ B3,
    OutT* __restrict__ C0, OutT* __restrict__ C1,
    OutT* __restrict__ C2, OutT* __restrict__ C3){
  constexpr int AI = BM / 64;
  constexpr int FI = BM / 32;
  constexpr int MT = (NQ == 4) ? 16 : 64;
  __shared__ u16 SA[2][BM * 64];
  __shared__ u16 SB[2][16384];
  int tid = threadIdx.x, lane = tid & 63, wave = tid >> 6;
  int g = lane >> 4, r15 = lane & 15;
  int id = blockIdx.x;
  int r8 = id & 7, k = id >> 3;
  int gm = (k >> 2) * 8 + r8;
  int ntile = k & 3;
  int quad = gm / MT;
  int mbase = (gm % MT) * BM, nbase = ntile * 256;
  const u16* A = quad==0?A0:quad==1?A1:quad==2?A2:A3;
  const u16* B = quad==0?B0:quad==1?B1:quad==2?B2:B3;
  OutT* C      = quad==0?C0:quad==1?C1:quad==2?C2:C3;
  int wr = wave >> 2, wc = wave & 3;
  int rsub = lane >> 3;
  int slo  = (lane & 7) ^ ((lane >> 3) & 7);
  int sw8  = (r15 & 7) << 3;
  f32x4 acc[FI][4] = {};

#define STG(kt, b) { \
  int ko = (kt) * 64; \
  _Pragma("unroll") \
  for (int i = 0; i < AI; ++i){ \
    int row = i*64 + wave*8 + rsub; \
    load_lds16(A + (size_t)(mbase + row)*1024 + ko + slo*8, &SA[b][(i*512 + wave*64)*8]); \
  } \
  _Pragma("unroll") \
  for (int i = 0; i < 4; ++i){ \
    int row = i*64 + wave*8 + rsub; \
    load_lds16(B + (size_t)(nbase + row)*1024 + ko + slo*8, &SB[b][(i*512 + wave*64)*8]); \
  } }

  STG(0, 0);
  for (int t = 0; t < 16; ++t){
    int b = t & 1;
    if (t < 15){
      STG(t + 1, b ^ 1);
      if constexpr (AI == 4) asm volatile("s_waitcnt vmcnt(8)" ::: "memory");
      else                   asm volatile("s_waitcnt vmcnt(6)" ::: "memory");
    } else {
      asm volatile("s_waitcnt vmcnt(0)" ::: "memory");
    }
    __builtin_amdgcn_s_barrier();
    __builtin_amdgcn_sched_barrier(0);
    const u16* Al = &SA[b][0];
    const u16* Bl = &SB[b][0];
#pragma unroll
    for (int ks = 0; ks < 2; ++ks){
      bf16x8 af[FI], bfr[4];
#pragma unroll
      for (int fi = 0; fi < FI; ++fi)
        af[fi] = *(const bf16x8*)&Al[(wr*(FI*16) + fi*16 + r15)*64 + ((ks*32 + g*8) ^ sw8)];
#pragma unroll
      for (int fj = 0; fj < 4; ++fj)
        bfr[fj] = *(const bf16x8*)&Bl[(wc*64 + fj*16 + r15)*64 + ((ks*32 + g*8) ^ sw8)];
#pragma unroll
      for (int fi = 0; fi < FI; ++fi)
#pragma unroll
        for (int fj = 0; fj < 4; ++fj)
          acc[fi][fj] = MFMA16(af[fi], bfr[fj], acc[fi][fj]);
    }
    __builtin_amdgcn_s_barrier();
  }
#undef STG

  bool tr = (TMASK >> quad) & 1;
#pragma unroll
  for (int fi = 0; fi < FI; ++fi)
#pragma unroll
    for (int fj = 0; fj < 4; ++fj)
#pragma unroll
      for (int r = 0; r < 4; ++r){
        int row = mbase + wr*(FI*16) + fi*16 + g*4 + r;
        int col = nbase + wc*64 + fj*16 + r15;
        if constexpr (TMASK != 0){
          if (tr){
            int bb = row >> 10, token = row & 1023;
            int hh = col >> 6,  dd = col & 63;
            storeC(&C[((size_t)((bb << 4) + hh) * 64 + dd) * 1024 + token], acc[fi][fj][r]);
            continue;
          }
        }
        storeC(&C[(size_t)row * 1024 + col], acc[fi][fj][r]);
      }
}

// ---------------- 8-phase 256x256 proj GEMM (R13-proven) ----------------
template<int TMASK>
__global__ __launch_bounds__(512, 2) void gemm8p(
    const u16* __restrict__ A0, const u16* __restrict__ A1,
    const u16* __restrict__ A2, const u16* __restrict__ A3,
    const u16* __restrict__ B0, const u16* __restrict__ B1,
    const u16* __restrict__ B2, const u16* __restrict__ B3,
    u16* __restrict__ C0, u16* __restrict__ C1,
    u16* __restrict__ C2, u16* __restrict__ C3){
  __shared__ u16 SL[2][2][2][8192];
  int tid = threadIdx.x, lane = tid & 63, wave = tid >> 6;
  int g = lane >> 4, r15 = lane & 15;
  int id = blockIdx.x;
  int r8 = id & 7, k = id >> 3;
  int gm = (k >> 2) * 8 + r8;
  int ntile = k & 3;
  int quad = gm >> 4;
  int mbase = (gm & 15) * 256, nbase = ntile * 256;
  const u16* A = quad==0?A0:quad==1?A1:quad==2?A2:A3;
  const u16* B = quad==0?B0:quad==1?B1:quad==2?B2:B3;
  u16* C       = quad==0?C0:quad==1?C1:quad==2?C2:C3;
  int wr = wave >> 2, wc = wave & 3;
  int X = (r15 & 3) ^ ((r15 >> 2) & 3);
  int rdc = (g ^ X) * 8;
  int srA = wave * 16 + (lane >> 2);
  int csrc = ((lane & 3) ^ ((lane >> 2) & 3) ^ ((lane >> 4) & 3)) * 8;
  f32x4 acc[8][4] = {};
  bf16x8 af[4], bfr[4];

#define ST8(P, tb, kt, kh, m, db) { \
  load_lds16(P + (size_t)((tb) + srA)*1024 + (kt)*64 + (kh)*32 + csrc,       &SL[m][db][kh][wave*512]); \
  load_lds16(P + (size_t)((tb) + 128 + srA)*1024 + (kt)*64 + (kh)*32 + csrc, &SL[m][db][kh][4096 + wave*512]); }

#define RD_A(db, kh, bfi) { \
  _Pragma("unroll") \
  for (int q = 0; q < 4; ++q) \
    af[q] = *(const bf16x8*)&SL[0][db][kh][(wr*128 + ((bfi)+q)*16 + r15)*32 + rdc]; }

#define RD_B(db, kh) { \
  _Pragma("unroll") \
  for (int q = 0; q < 4; ++q) \
    bfr[q] = *(const bf16x8*)&SL[1][db][kh][(wc*64 + q*16 + r15)*32 + rdc]; }

#define MM8(bfi) { \
  _Pragma("unroll") \
  for (int q = 0; q < 4; ++q) \
    _Pragma("unroll") \
    for (int fj = 0; fj < 4; ++fj) \
      acc[(bfi)+q][fj] = MFMA16(af[q], bfr[fj], acc[(bfi)+q][fj]); }

#define PH(db, kh, half, STAGE, WAIT) { \
  if ((half) == 0) RD_B(db, kh); \
  RD_A(db, kh, (half)*4); \
  STAGE; \
  WAIT; \
  __builtin_amdgcn_s_barrier(); \
  asm volatile("s_waitcnt lgkmcnt(0)" ::: "memory"); \
  __builtin_amdgcn_sched_barrier(0); \
  __builtin_amdgcn_s_setprio(1); \
  MM8((half)*4); \
  __builtin_amdgcn_s_setprio(0); \
  __builtin_amdgcn_s_barrier(); }

  ST8(A, mbase, 0, 0, 0, 0); ST8(B, nbase, 0, 0, 1, 0);
  ST8(A, mbase, 0, 1, 0, 0); ST8(B, nbase, 0, 1, 1, 0);
  ST8(A, mbase, 1, 0, 0, 1); ST8(B, nbase, 1, 0, 1, 1);
  asm volatile("s_waitcnt vmcnt(4)" ::: "memory");
  __builtin_amdgcn_s_barrier();

  for (int i = 0; i < 8; ++i){
    int t1 = 2*i + 1, t2 = 2*i + 2, t3 = 2*i + 3;
    bool more = (i < 7);
    PH(0, 0, 0, ST8(A, mbase, t1, 1, 0, 1), {});
    PH(0, 0, 1, ST8(B, nbase, t1, 1, 1, 1), {});
    PH(0, 1, 0, { if (more) ST8(A, mbase, t2, 0, 0, 0); }, {});
    PH(0, 1, 1, { if (more) ST8(B, nbase, t2, 0, 1, 0); },
                { if (more) asm volatile("s_waitcnt vmcnt(4)" ::: "memory");
                  else      asm volatile("s_waitcnt vmcnt(0)" ::: "memory"); });
    PH(1, 0, 0, { if (more) ST8(A, mbase, t2, 1, 0, 0); }, {});
    PH(1, 0, 1, { if (more) ST8(B, nbase, t2, 1, 1, 0); }, {});
    PH(1, 1, 0, { if (more) ST8(A, mbase, t3, 0, 0, 1); }, {});
    PH(1, 1, 1, { if (more) ST8(B, nbase, t3, 0, 1, 1); },
                { if (more) asm volatile("s_waitcnt vmcnt(4)" ::: "memory"); });
  }
#undef PH
#undef MM8
#undef RD_B
#undef RD_A
#undef ST8

  bool tr = (TMASK >> quad) & 1;
#pragma unroll
  for (int fi = 0; fi < 8; ++fi)
#pragma unroll
    for (int fj = 0; fj < 4; ++fj)
#pragma unroll
      for (int r = 0; r < 4; ++r){
        int row = mbase + wr*128 + fi*16 + g*4 + r;
        int col = nbase + wc*64 + fj*16 + r15;
        if (tr){
          int bb = row >> 10, token = row & 1023;
          int hh = col >> 6,  dd = col & 63;
          storeC(&C[((size_t)((bb << 4) + hh) * 64 + dd) * 1024 + token], acc[fi][fj][r]);
        } else {
          storeC(&C[(size_t)row * 1024 + col], acc[fi][fj][r]);
        }
      }
}

// ---------------- flash attention: KV-split waves, zero-LDS zero-barrier main loop ----
// 1D grid 2048, XCD-bijective decode. Each wave owns a 16-kv slice and ALL 64 q
// rows (Q hoisted to regs). K/V fragments read directly from global (XCD-L2-
// resident panels). QK^T C-layout (row=4g+r ↔ kv, col=r15 ↔ q) IS the PV
// B-operand layout -> no exchange shuffles; PV contracts kv 32-at-a-time over
// pairs of kv-tiles. Cross-wave acc/l reduction via 17KB LDS epilogue.
__global__ __launch_bounds__(256) void flash(const u16* __restrict__ qg, const u16* __restrict__ vTg,
                                             const u16* __restrict__ kag, const u16* __restrict__ vaTg,
                                             u16* __restrict__ xu, u16* __restrict__ xau){
  __shared__ float RED[64][65];    // [d][q] accumulator partials
  __shared__ float REDL[4][64];    // [qg][q] l partials
  int tid = threadIdx.x, lane = tid & 63, wave = tid >> 6, g = lane >> 4, r15 = lane & 15;
  int b = blockIdx.x;
  int xcd = b & 7, idx = b >> 3;
  int qt = idx & 15;
  int pair = xcd * 16 + (idx >> 4);
  int bh = pair & 63, dir = pair >> 6;
  size_t tokbase = ((size_t)(bh >> 4)) * 1048576 + (size_t)(bh & 15) * 64;
  size_t vtbase  = (size_t)bh << 16;
  const u16 *Q, *K, *VT; u16* O;
  if (dir == 0){ Q = qg + tokbase;  K = kag + tokbase; VT = vaTg + vtbase; O = xu  + tokbase; }
  else         { Q = kag + tokbase; K = qg  + tokbase; VT = vTg  + vtbase; O = xau + tokbase; }
  Q += (size_t)qt * 65536;
  O += (size_t)qt * 65536;

  // hoist all 4 q-group fragments (B-operand: col q=r15, k=d=8g+e per 32-half)
  bf16x8 qf[4][2];
#pragma unroll
  for (int qg_ = 0; qg_ < 4; ++qg_){
    const u16* Qrow = Q + (size_t)(qg_*16 + r15) * 1024 + g*8;
    qf[qg_][0] = *(const bf16x8*)(Qrow);
    qf[qg_][1] = *(const bf16x8*)(Qrow + 32);
  }

  int kvb = wave * 16;                    // wave's kv slice within each 64-tile
  f32x4 acc[4][4] = {};                   // [nb: d-group][qg]; C: row d=nb*16+4g+r, col q=qg*16+r15
  float pl[4] = {};
  const f32x4 zinit = {-32.f, -32.f, -32.f, -32.f};

  for (int j = 0; j < 16; j += 2){
    u32 pk[2][4][2];                      // [sub-tile][qg][pair] - static-indexed (unrolled)
#pragma unroll
    for (int s = 0; s < 2; ++s){
      const u16* Krow = K + (size_t)((j + s)*64 + kvb + r15) * 1024 + g*8;
      bf16x8 kf0 = *(const bf16x8*)(Krow);         // A: row kv=kvb+r15, k=d=8g+e
      bf16x8 kf1 = *(const bf16x8*)(Krow + 32);
#pragma unroll
      for (int qg_ = 0; qg_ < 4; ++qg_){
        f32x4 z = MFMA16(kf0, qf[qg_][0], zinit);  // S' - 32
        z = MFMA16(kf1, qf[qg_][1], z);
        float p0 = __builtin_amdgcn_exp2f(z[0]);
        float p1 = __builtin_amdgcn_exp2f(z[1]);
        float p2 = __builtin_amdgcn_exp2f(z[2]);
        float p3 = __builtin_amdgcn_exp2f(z[3]);
        pl[qg_] += (p0 + p1) + (p2 + p3);
        pk[s][qg_][0] = cvtpk(p0, p1);             // k-elems 0,1 (kv 4g+0,4g+1 of tile j+s)
        pk[s][qg_][1] = cvtpk(p2, p3);             // k-elems 2,3
      }
    }
    // PV over 32-kv super-tile: k=8g+e; e<4 -> tile j, e>=4 -> tile j+1 (same map in vf)
#pragma unroll
    for (int nb = 0; nb < 4; ++nb){
      const u16* Vrow = VT + (size_t)(nb*16 + r15) * 1024 + kvb + 4*g;
      union { u32 w[4]; bf16x8 v; } vf;
      *(u16x4*)&vf.w[0] = *(const u16x4*)(Vrow + j*64);
      *(u16x4*)&vf.w[2] = *(const u16x4*)(Vrow + (j + 1)*64);
#pragma unroll
      for (int qg_ = 0; qg_ < 4; ++qg_){
        union { u32 w[4]; bf16x8 v; } pf;
        pf.w[0] = pk[0][qg_][0]; pf.w[1] = pk[0][qg_][1];
        pf.w[2] = pk[1][qg_][0]; pf.w[3] = pk[1][qg_][1];
        acc[nb][qg_] = MFMA16(vf.v, pf.v, acc[nb][qg_]);
      }
    }
  }

  // cross-g reduce of l: lane then holds wave-partial l for q = qg*16+r15
#pragma unroll
  for (int qg_ = 0; qg_ < 4; ++qg_){
    pl[qg_] += __shfl_xor(pl[qg_], 16);
    pl[qg_] += __shfl_xor(pl[qg_], 32);
  }

  // cross-wave reduction: wave3 writes, wave2/wave1 RMW sequentially, wave0 finishes
  if (wave == 3){
#pragma unroll
    for (int nb = 0; nb < 4; ++nb)
#pragma unroll
      for (int qg_ = 0; qg_ < 4; ++qg_)
#pragma unroll
        for (int r = 0; r < 4; ++r)
          RED[nb*16 + 4*g + r][qg_*16 + r15] = acc[nb][qg_][r];
    if (g == 0)
#pragma unroll
      for (int qg_ = 0; qg_ < 4; ++qg_) REDL[qg_][r15] = pl[qg_];
  }
  __syncthreads();
  if (wave == 2){
#pragma unroll
    for (int nb = 0; nb < 4; ++nb)
#pragma unroll
      for (int qg_ = 0; qg_ < 4; ++qg_)
#pragma unroll
        for (int r = 0; r < 4; ++r)
          RED[nb*16 + 4*g + r][qg_*16 + r15] += acc[nb][qg_][r];
    if (g == 0)
#pragma unroll
      for (int qg_ = 0; qg_ < 4; ++qg_) REDL[qg_][r15] += pl[qg_];
  }
  __syncthreads();
  if (wave == 1){
#pragma unroll
    for (int nb = 0; nb < 4; ++nb)
#pragma unroll
      for (int qg_ = 0; qg_ < 4; ++qg_)
#pragma unroll
        for (int r = 0; r < 4; ++r)
          RED[nb*16 + 4*g + r][qg_*16 + r15] += acc[nb][qg_][r];
    if (g == 0)
#pragma unroll
      for (int qg_ = 0; qg_ < 4; ++qg_) REDL[qg_][r15] += pl[qg_];
  }
  __syncthreads();
  if (wave == 0){
    float inv[4];
#pragma unroll
    for (int qg_ = 0; qg_ < 4; ++qg_)
      inv[qg_] = 1.0f / (REDL[qg_][r15] + pl[qg_]);
#pragma unroll
    for (int qg_ = 0; qg_ < 4; ++qg_)
#pragma unroll
      for (int nb = 0; nb < 4; ++nb){
        u16x4 o;
        o.x = f2bf((acc[nb][qg_][0] + RED[nb*16 + 4*g + 0][qg_*16 + r15]) * inv[qg_]);
        o.y = f2bf((acc[nb][qg_][1] + RED[nb*16 + 4*g + 1][qg_*16 + r15]) * inv[qg_]);
        o.z = f2bf((acc[nb][qg_][2] + RED[nb*16 + 4*g + 2][qg_*16 + r15]) * inv[qg_]);
        o.w = f2bf((acc[nb][qg_][3] + RED[nb*16 + 4*g + 3][qg_*16 + r15]) * inv[qg_]);
        *(u16x4*)&O[(size_t)(qg_*16 + r15) * 1024 + nb*16 + 4*g] = o;
      }
  }
}

extern "C" void kernel_launch(void* const* d_in, const int* in_sizes, int n_in,
                              void* d_out, int out_size, void* d_ws, size_t ws_size,
                              hipStream_t stream){
  const float* x    = (const float*)d_in[0];
  const float* xa   = (const float*)d_in[1];
  const float* lnw  = (const float*)d_in[2];
  const float* lnb  = (const float*)d_in[3];
  const float* Wq   = (const float*)d_in[4];
  const float* Wkv  = (const float*)d_in[5];
  const float* Wout = (const float*)d_in[6];
  float* out = (float*)d_out;
  char* ws = (char*)d_ws;
  const size_t MB = 1ull << 20;
  u16* xn  = (u16*)(ws);
  u16* xan = (u16*)(ws + 8*MB);
  u16* q   = (u16*)(ws + 16*MB);
  u16* vT  = (u16*)(ws + 24*MB);
  u16* ka  = (u16*)(ws + 32*MB);
  u16* vaT = (u16*)(ws + 40*MB);
  u16* xu  = (u16*)(ws + 48*MB);   // xu..xau contiguous -> M=8192 out-GEMM
  u16* xau = (u16*)(ws + 56*MB);
  u16* WqT = (u16*)(ws + 64*MB);
  u16* WkT = (u16*)(ws + 66*MB);
  u16* WvT = (u16*)(ws + 68*MB);
  u16* WoT = (u16*)(ws + 70*MB);
  dim3 blk(256);
  transpose_all<<<dim3(16,16,4), blk, 0, stream>>>(Wq, Wkv, Wout, WqT, WkT, WvT, WoT);
  ln_cast<<<8192, blk, 0, stream>>>(x, xa, lnw, lnb, xn, xan);
  // proj (8-phase): quads 0:q, 1:vT(tr), 2:ka, 3:vaT(tr). 1-D 256 blocks, XCD-grouped.
  gemm8p<0xA><<<dim3(256), dim3(512), 0, stream>>>(
      xn, xn, xan, xan, WqT, WvT, WkT, WvT, q, vT, ka, vaT);
  flash<<<dim3(2048), blk, 0, stream>>>(q, vT, ka, vaT, xu, xau);
  // out: single M=8192 GEMM (xu||xau) @ WoT -> (out0||out1) f32. 256 blocks, 2-phase.
  gemm256<128, 1, 0, float><<<dim3(256), dim3(512), 0, stream>>>(
      xu, xu, xu, xu, WoT, WoT, WoT, WoT, out, out, out, out);
}

// Round 16
// 163.790 us; speedup vs baseline: 1.2657x; 1.2657x over previous
//
#include <hip/hip_runtime.h>
#include <hip/hip_bf16.h>

typedef unsigned short u16;
typedef unsigned int u32;
typedef __attribute__((ext_vector_type(4))) unsigned short u16x4;
typedef __attribute__((ext_vector_type(8))) unsigned short u16x8;
typedef __attribute__((ext_vector_type(8))) __bf16 bf16x8;
typedef __attribute__((ext_vector_type(4))) float f32x4;

__device__ __forceinline__ u16 f2bf(float f){
  unsigned u = __builtin_bit_cast(unsigned, f);
  u += 0x7FFFu + ((u >> 16) & 1u);
  return (u16)(u >> 16);
}

__device__ __forceinline__ u32 cvtpk(float lo, float hi){
  u32 r;
  asm("v_cvt_pk_bf16_f32 %0, %1, %2" : "=v"(r) : "v"(lo), "v"(hi));
  return r;
}

__device__ __forceinline__ void load_lds16(const void* g, void* l){
  __builtin_amdgcn_global_load_lds((const __attribute__((address_space(1))) unsigned*)g,
                                   (__attribute__((address_space(3))) unsigned*)l, 16, 0, 0);
}

__device__ __forceinline__ void storeC(float* p, float v){ *p = v; }
__device__ __forceinline__ void storeC(u16* p, float v){ *p = f2bf(v); }

// ---------------- all 4 weight transposes in one launch ----------------
// Wq is additionally scaled by log2(e): scores then live in the exp2 domain.
__global__ __launch_bounds__(256) void transpose_all(const float* __restrict__ Wq,
                                                     const float* __restrict__ Wkv,
                                                     const float* __restrict__ Wout,
                                                     u16* __restrict__ WqT, u16* __restrict__ WkT,
                                                     u16* __restrict__ WvT, u16* __restrict__ WoT){
  const float* in; u16* out; int ldin;
  switch (blockIdx.z){
    case 0:  in = Wq;         out = WqT; ldin = 1024; break;
    case 1:  in = Wkv;        out = WkT; ldin = 2048; break;
    case 2:  in = Wkv + 1024; out = WvT; ldin = 2048; break;
    default: in = Wout;       out = WoT; ldin = 1024; break;
  }
  float scl = (blockIdx.z == 0) ? 1.44269504f : 1.0f;
  __shared__ float tile[64][65];
  int t = threadIdx.x;
  int tr = blockIdx.y * 64, tc = blockIdx.x * 64;
  int r0 = t >> 4, c0 = (t & 15) * 4;
#pragma unroll
  for (int i = 0; i < 4; ++i){
    int r = r0 + i * 16;
    const float4 val = *(const float4*)&in[(size_t)(tr + r) * ldin + tc + c0];
    tile[r][c0] = val.x; tile[r][c0+1] = val.y; tile[r][c0+2] = val.z; tile[r][c0+3] = val.w;
  }
  __syncthreads();
#pragma unroll
  for (int i = 0; i < 4; ++i){
    int n = r0 + i * 16;
    u16x4 o4;
    o4.x = f2bf(tile[c0+0][n] * scl); o4.y = f2bf(tile[c0+1][n] * scl);
    o4.z = f2bf(tile[c0+2][n] * scl); o4.w = f2bf(tile[c0+3][n] * scl);
    *(u16x4*)&out[(size_t)(tc + n) * 1024 + tr + c0] = o4;
  }
}

// ---------------- layernorm + bf16 cast, one row per block ----------------
__global__ __launch_bounds__(256) void ln_cast(const float* __restrict__ x, const float* __restrict__ xa,
                                               const float* __restrict__ w, const float* __restrict__ bb,
                                               u16* __restrict__ xn, u16* __restrict__ xan){
  int row = blockIdx.x;
  const float* src; u16* dst;
  if (row < 4096){ src = x + (size_t)row * 1024; dst = xn + (size_t)row * 1024; }
  else { src = xa + (size_t)(row - 4096) * 1024; dst = xan + (size_t)(row - 4096) * 1024; }
  int t = threadIdx.x;
  float4 v = ((const float4*)src)[t];
  float s = v.x + v.y + v.z + v.w;
  float ss = v.x*v.x + v.y*v.y + v.z*v.z + v.w*v.w;
#pragma unroll
  for (int o = 32; o > 0; o >>= 1){ s += __shfl_down(s, o); ss += __shfl_down(ss, o); }
  __shared__ float red[8];
  int wv = t >> 6;
  if ((t & 63) == 0){ red[wv] = s; red[wv + 4] = ss; }
  __syncthreads();
  if (t == 0){
    red[0] = red[0] + red[1] + red[2] + red[3];
    red[4] = red[4] + red[5] + red[6] + red[7];
  }
  __syncthreads();
  float mu = red[0] * (1.0f/1024.0f);
  float var = red[4] * (1.0f/1024.0f) - mu*mu;
  float rstd = rsqrtf(var + 1e-5f);
  float4 wv4 = ((const float4*)w)[t];
  float4 bv4 = ((const float4*)bb)[t];
  u16x4 o4;
  o4.x = f2bf((v.x - mu) * rstd * wv4.x + bv4.x);
  o4.y = f2bf((v.y - mu) * rstd * wv4.y + bv4.y);
  o4.z = f2bf((v.z - mu) * rstd * wv4.z + bv4.z);
  o4.w = f2bf((v.w - mu) * rstd * wv4.w + bv4.w);
  ((u16x4*)dst)[t] = o4;
}

// ---------------- BMx256 GEMM, BK=64, 8 waves, dbuf, counted vmcnt (R8/R11-proven) ----
template<int BM, int NQ, int TMASK, typename OutT>
__global__ __launch_bounds__(512, 2) void gemm256(
    const u16* __restrict__ A0, const u16* __restrict__ A1,
    const u16* __restrict__ A2, const u16* __restrict__ A3,
    const u16* __restrict__ B0, const u16* __restrict__ B1,
    const u16* __restrict__ B2, const u16* __restrict__ B3,
    OutT* __restrict__ C0, OutT* __restrict__ C1,
    OutT* __restrict__ C2, OutT* __restrict__ C3){
  constexpr int AI = BM / 64;
  constexpr int FI = BM / 32;
  constexpr int MT = (NQ == 4) ? 16 : 64;
  __shared__ u16 SA[2][BM * 64];
  __shared__ u16 SB[2][16384];
  int tid = threadIdx.x, lane = tid & 63, wave = tid >> 6;
  int g = lane >> 4, r15 = lane & 15;
  int id = blockIdx.x;
  int r8 = id & 7, k = id >> 3;
  int gm = (k >> 2) * 8 + r8;
  int ntile = k & 3;
  int quad = gm / MT;
  int mbase = (gm % MT) * BM, nbase = ntile * 256;
  const u16* A = quad==0?A0:quad==1?A1:quad==2?A2:A3;
  const u16* B = quad==0?B0:quad==1?B1:quad==2?B2:B3;
  OutT* C      = quad==0?C0:quad==1?C1:quad==2?C2:C3;
  int wr = wave >> 2, wc = wave & 3;
  int rsub = lane >> 3;
  int slo  = (lane & 7) ^ ((lane >> 3) & 7);
  int sw8  = (r15 & 7) << 3;
  f32x4 acc[FI][4] = {};

#define STG(kt, b) { \
  int ko = (kt) * 64; \
  _Pragma("unroll") \
  for (int i = 0; i < AI; ++i){ \
    int row = i*64 + wave*8 + rsub; \
    load_lds16(A + (size_t)(mbase + row)*1024 + ko + slo*8, &SA[b][(i*512 + wave*64)*8]); \
  } \
  _Pragma("unroll") \
  for (int i = 0; i < 4; ++i){ \
    int row = i*64 + wave*8 + rsub; \
    load_lds16(B + (size_t)(nbase + row)*1024 + ko + slo*8, &SB[b][(i*512 + wave*64)*8]); \
  } }

  STG(0, 0);
  for (int t = 0; t < 16; ++t){
    int b = t & 1;
    if (t < 15){
      STG(t + 1, b ^ 1);
      if constexpr (AI == 4) asm volatile("s_waitcnt vmcnt(8)" ::: "memory");
      else                   asm volatile("s_waitcnt vmcnt(6)" ::: "memory");
    } else {
      asm volatile("s_waitcnt vmcnt(0)" ::: "memory");
    }
    __builtin_amdgcn_s_barrier();
    __builtin_amdgcn_sched_barrier(0);
    const u16* Al = &SA[b][0];
    const u16* Bl = &SB[b][0];
#pragma unroll
    for (int ks = 0; ks < 2; ++ks){
      bf16x8 af[FI], bfr[4];
#pragma unroll
      for (int fi = 0; fi < FI; ++fi)
        af[fi] = *(const bf16x8*)&Al[(wr*(FI*16) + fi*16 + r15)*64 + ((ks*32 + g*8) ^ sw8)];
#pragma unroll
      for (int fj = 0; fj < 4; ++fj)
        bfr[fj] = *(const bf16x8*)&Bl[(wc*64 + fj*16 + r15)*64 + ((ks*32 + g*8) ^ sw8)];
#pragma unroll
      for (int fi = 0; fi < FI; ++fi)
#pragma unroll
        for (int fj = 0; fj < 4; ++fj)
          acc[fi][fj] = __builtin_amdgcn_mfma_f32_16x16x32_bf16(af[fi], bfr[fj], acc[fi][fj], 0, 0, 0);
    }
    __builtin_amdgcn_s_barrier();
  }
#undef STG

  bool tr = (TMASK >> quad) & 1;
#pragma unroll
  for (int fi = 0; fi < FI; ++fi)
#pragma unroll
    for (int fj = 0; fj < 4; ++fj)
#pragma unroll
      for (int r = 0; r < 4; ++r){
        int row = mbase + wr*(FI*16) + fi*16 + g*4 + r;
        int col = nbase + wc*64 + fj*16 + r15;
        if constexpr (TMASK != 0){
          if (tr){
            int bb = row >> 10, token = row & 1023;
            int hh = col >> 6,  dd = col & 63;
            storeC(&C[((size_t)((bb << 4) + hh) * 64 + dd) * 1024 + token], acc[fi][fj][r]);
            continue;
          }
        }
        storeC(&C[(size_t)row * 1024 + col], acc[fi][fj][r]);
      }
}

// ---------------- flash attention, both directions ----------------
// 1D grid 2048, XCD-bijective decode. 256 thr, 4 waves x 16 q-rows.
// DS-pipe diet: K/VT staged via global_load_lds (pre-swizzled source, linear
// dest), LDS double-buffered with counted vmcnt(4) across raw barriers (gemm's
// proven protocol). l-reduction deferred to epilogue. No-max exp2 softmax.
#define SW(row, col) ((row) * 64 + ((col) ^ (((row) & 7) << 3)))

__device__ __forceinline__ void exchP(const f32x4& s0, const f32x4& s1,
                                      const f32x4& s2, const f32x4& s3,
                                      bool gh, bool g0, bf16x8& pf0, bf16x8& pf1){
  u32 pk00 = cvtpk(s0[0], s0[1]), pk01 = cvtpk(s0[2], s0[3]);
  u32 pk10 = cvtpk(s1[0], s1[1]), pk11 = cvtpk(s1[2], s1[3]);
  u32 pk20 = cvtpk(s2[0], s2[1]), pk21 = cvtpk(s2[2], s2[3]);
  u32 pk30 = cvtpk(s3[0], s3[1]), pk31 = cvtpk(s3[2], s3[3]);
  u32 c0 = gh ? pk10 : pk00, c1 = gh ? pk11 : pk01;
  u32 d0 = gh ? pk00 : pk10, d1 = gh ? pk01 : pk11;
  u32 s1a = __shfl_xor((int)c0, 16), s1b = __shfl_xor((int)c1, 16);
  u32 s2a = __shfl_xor((int)d0, 32), s2b = __shfl_xor((int)d1, 32);
  u32 s3a = __shfl_xor((int)d0, 48), s3b = __shfl_xor((int)d1, 48);
  union UB { u32 w[4]; bf16x8 v; } ub0, ub1;
  ub0.w[0] = gh ? (g0 ? s1a : s2a) : (g0 ? s3a : c0);
  ub0.w[1] = gh ? (g0 ? s1b : s2b) : (g0 ? s3b : c1);
  ub0.w[2] = gh ? (g0 ? c0 : s3a) : (g0 ? s2a : s1a);
  ub0.w[3] = gh ? (g0 ? c1 : s3b) : (g0 ? s2b : s1b);
  u32 e0 = gh ? pk30 : pk20, e1 = gh ? pk31 : pk21;
  u32 f0 = gh ? pk20 : pk30, f1 = gh ? pk21 : pk31;
  u32 t1a = __shfl_xor((int)e0, 16), t1b = __shfl_xor((int)e1, 16);
  u32 t2a = __shfl_xor((int)f0, 32), t2b = __shfl_xor((int)f1, 32);
  u32 t3a = __shfl_xor((int)f0, 48), t3b = __shfl_xor((int)f1, 48);
  ub1.w[0] = gh ? (g0 ? t1a : t2a) : (g0 ? t3a : e0);
  ub1.w[1] = gh ? (g0 ? t1b : t2b) : (g0 ? t3b : e1);
  ub1.w[2] = gh ? (g0 ? e0 : t3a) : (g0 ? t2a : t1a);
  ub1.w[3] = gh ? (g0 ? e1 : t3b) : (g0 ? t2b : t1b);
  pf0 = ub0.v; pf1 = ub1.v;
}

#define MFMA16(a, b, c) __builtin_amdgcn_mfma_f32_16x16x32_bf16(a, b, c, 0, 0, 0)

__global__ __launch_bounds__(256) void flash(const u16* __restrict__ qg, const u16* __restrict__ vTg,
                                             const u16* __restrict__ kag, const u16* __restrict__ vaTg,
                                             u16* __restrict__ xu, u16* __restrict__ xau){
  __shared__ u16 Ks[2][4096], VTs[2][4096];
  int tid = threadIdx.x, lane = tid & 63, wave = tid >> 6, g = lane >> 4, r15 = lane & 15;
  int b = blockIdx.x;
  int xcd = b & 7, idx = b >> 3;
  int qt = idx & 15;
  int pair = xcd * 16 + (idx >> 4);
  int bh = pair & 63, dir = pair >> 6;
  size_t tokbase = ((size_t)(bh >> 4)) * 1048576 + (size_t)(bh & 15) * 64;
  size_t vtbase  = (size_t)bh << 16;
  const u16 *Q, *K, *VT; u16* O;
  if (dir == 0){ Q = qg + tokbase;  K = kag + tokbase; VT = vaTg + vtbase; O = xu  + tokbase; }
  else         { Q = kag + tokbase; K = qg  + tokbase; VT = vTg  + vtbase; O = xau + tokbase; }
  Q += (size_t)qt * 64 * 1024;
  O += (size_t)qt * 64 * 1024;

  int wq = wave * 16;
  bf16x8 qf0 = *(const bf16x8*)&Q[(size_t)(wq + r15) * 1024 + g*8];
  bf16x8 qf1 = *(const bf16x8*)&Q[(size_t)(wq + r15) * 1024 + 32 + g*8];

  // staging source (pre-swizzled): row = wave*8 + i*32 + rl, chunk = (lane&7)^rl
  // (row&7 == rl since wave*8 and i*32 are 0 mod 8); LDS dest linear.
  int rl = lane >> 3;
  int ch = (lane & 7) ^ rl;
  const u16* Kb = K  + (size_t)(wave*8 + rl) * 1024 + ch*8;
  const u16* Vb = VT + (size_t)(wave*8 + rl) * 1024 + ch*8;

#define FSTG(j, buf) { \
  load_lds16(Kb + (size_t)(j)*65536,                 &Ks [buf][(wave*8)*64]); \
  load_lds16(Kb + (size_t)(j)*65536 + 32*1024,       &Ks [buf][(wave*8 + 32)*64]); \
  load_lds16(Vb + (j)*64,                            &VTs[buf][(wave*8)*64]); \
  load_lds16(Vb + (j)*64 + (size_t)32*1024,          &VTs[buf][(wave*8 + 32)*64]); \
}

  float pl = 0.0f;                      // per-lane l partial; cross-g reduce deferred
  f32x4 acc[4] = {};
  bool gh = g >= 2, g0 = g & 1;
  const f32x4 zinit = {-32.f, -32.f, -32.f, -32.f};

  FSTG(0, 0);
  for (int j = 0; j < 16; ++j){
    int buf = j & 1;
    if (j < 15){
      FSTG(j + 1, buf ^ 1);             // writes buf read LAST iter (safe past its barrier)
      asm volatile("s_waitcnt vmcnt(4)" ::: "memory");  // tile j landed; j+1 in flight
    } else {
      asm volatile("s_waitcnt vmcnt(0)" ::: "memory");
    }
    __builtin_amdgcn_s_barrier();       // tile j visible to all waves
    __builtin_amdgcn_sched_barrier(0);
    const u16* kb = &Ks[buf][0];
    const u16* vb = &VTs[buf][0];

    // S' - 32 = K Q^T + (-32): rows kv = 16*kvi + 4g + reg, col q = r15
    f32x4 sf[4];
    __builtin_amdgcn_s_setprio(1);
#pragma unroll
    for (int kvi = 0; kvi < 4; ++kvi){
      bf16x8 kf0 = *(const bf16x8*)&kb[SW(kvi*16 + r15, g*8)];
      bf16x8 kf1 = *(const bf16x8*)&kb[SW(kvi*16 + r15, 32 + g*8)];
      f32x4 z = MFMA16(kf0, qf0, zinit);
      z = MFMA16(kf1, qf1, z);
      sf[kvi] = z;
    }
    __builtin_amdgcn_s_setprio(0);

    // P = exp2(S' - 32); per-lane partial sum only
#pragma unroll
    for (int kvi = 0; kvi < 4; ++kvi)
#pragma unroll
      for (int r = 0; r < 4; ++r){
        float p = __builtin_amdgcn_exp2f(sf[kvi][r]);
        sf[kvi][r] = p; pl += p;
      }

    bf16x8 pf0, pf1;
    exchP(sf[0], sf[1], sf[2], sf[3], gh, g0, pf0, pf1);

    // PV: out^T[d][q] += V^T[d][kv] * P^T
    __builtin_amdgcn_s_setprio(1);
#pragma unroll
    for (int nb = 0; nb < 4; ++nb){
      bf16x8 vf0 = *(const bf16x8*)&vb[SW(nb*16 + r15, g*8)];
      acc[nb] = MFMA16(vf0, pf0, acc[nb]);
    }
#pragma unroll
    for (int nb = 0; nb < 4; ++nb){
      bf16x8 vf1 = *(const bf16x8*)&vb[SW(nb*16 + r15, 32 + g*8)];
      acc[nb] = MFMA16(vf1, pf1, acc[nb]);
    }
    __builtin_amdgcn_s_setprio(0);
    __builtin_amdgcn_s_barrier();       // reads of buf done -> next iter may stage into buf^1
  }
#undef FSTG

  // epilogue: one cross-g reduce for l, then normalize + store
  pl += __shfl_xor(pl, 16);
  pl += __shfl_xor(pl, 32);
  float inv = 1.0f / pl;
  size_t orow = (size_t)(wq + r15) * 1024;
#pragma unroll
  for (int nb = 0; nb < 4; ++nb){
    u16x4 o;
    o.x = f2bf(acc[nb][0] * inv);
    o.y = f2bf(acc[nb][1] * inv);
    o.z = f2bf(acc[nb][2] * inv);
    o.w = f2bf(acc[nb][3] * inv);
    *(u16x4*)&O[orow + nb*16 + g*4] = o;
  }
}

extern "C" void kernel_launch(void* const* d_in, const int* in_sizes, int n_in,
                              void* d_out, int out_size, void* d_ws, size_t ws_size,
                              hipStream_t stream){
  const float* x    = (const float*)d_in[0];
  const float* xa   = (const float*)d_in[1];
  const float* lnw  = (const float*)d_in[2];
  const float* lnb  = (const float*)d_in[3];
  const float* Wq   = (const float*)d_in[4];
  const float* Wkv  = (const float*)d_in[5];
  const float* Wout = (const float*)d_in[6];
  float* out = (float*)d_out;
  char* ws = (char*)d_ws;
  const size_t MB = 1ull << 20;
  u16* xn  = (u16*)(ws);
  u16* xan = (u16*)(ws + 8*MB);
  u16* q   = (u16*)(ws + 16*MB);
  u16* vT  = (u16*)(ws + 24*MB);
  u16* ka  = (u16*)(ws + 32*MB);
  u16* vaT = (u16*)(ws + 40*MB);
  u16* xu  = (u16*)(ws + 48*MB);   // xu..xau contiguous -> M=8192 out-GEMM
  u16* xau = (u16*)(ws + 56*MB);
  u16* WqT = (u16*)(ws + 64*MB);
  u16* WkT = (u16*)(ws + 66*MB);
  u16* WvT = (u16*)(ws + 68*MB);
  u16* WoT = (u16*)(ws + 70*MB);
  dim3 blk(256);
  transpose_all<<<dim3(16,16,4), blk, 0, stream>>>(Wq, Wkv, Wout, WqT, WkT, WvT, WoT);
  ln_cast<<<8192, blk, 0, stream>>>(x, xa, lnw, lnb, xn, xan);
  // proj: quads 0:q, 1:vT(tr), 2:ka, 3:vaT(tr). 1-D 256 blocks, XCD-grouped.
  gemm256<256, 4, 0xA, u16><<<dim3(256), dim3(512), 0, stream>>>(
      xn, xn, xan, xan, WqT, WvT, WkT, WvT, q, vT, ka, vaT);
  flash<<<dim3(2048), blk, 0, stream>>>(q, vT, ka, vaT, xu, xau);
  // out: single M=8192 GEMM (xu||xau) @ WoT -> (out0||out1) f32. 256 blocks.
  gemm256<128, 1, 0, float><<<dim3(256), dim3(512), 0, stream>>>(
      xu, xu, xu, xu, WoT, WoT, WoT, WoT, out, out, out, out);
}

// Round 17
// 144.581 us; speedup vs baseline: 1.4339x; 1.1329x over previous
//
#include <hip/hip_runtime.h>
#include <hip/hip_bf16.h>

typedef unsigned short u16;
typedef unsigned int u32;
typedef __attribute__((ext_vector_type(4))) unsigned short u16x4;
typedef __attribute__((ext_vector_type(8))) unsigned short u16x8;
typedef __attribute__((ext_vector_type(8))) __bf16 bf16x8;
typedef __attribute__((ext_vector_type(4))) float f32x4;

__device__ __forceinline__ u16 f2bf(float f){
  unsigned u = __builtin_bit_cast(unsigned, f);
  u += 0x7FFFu + ((u >> 16) & 1u);
  return (u16)(u >> 16);
}

__device__ __forceinline__ u32 cvtpk(float lo, float hi){
  u32 r;
  asm("v_cvt_pk_bf16_f32 %0, %1, %2" : "=v"(r) : "v"(lo), "v"(hi));
  return r;
}

__device__ __forceinline__ void load_lds16(const void* g, void* l){
  __builtin_amdgcn_global_load_lds((const __attribute__((address_space(1))) unsigned*)g,
                                   (__attribute__((address_space(3))) unsigned*)l, 16, 0, 0);
}

__device__ __forceinline__ void storeC(float* p, float v){ *p = v; }
__device__ __forceinline__ void storeC(u16* p, float v){ *p = f2bf(v); }

// ---------------- all 4 weight transposes in one launch ----------------
// Wq is additionally scaled by log2(e): scores then live in the exp2 domain.
__global__ __launch_bounds__(256) void transpose_all(const float* __restrict__ Wq,
                                                     const float* __restrict__ Wkv,
                                                     const float* __restrict__ Wout,
                                                     u16* __restrict__ WqT, u16* __restrict__ WkT,
                                                     u16* __restrict__ WvT, u16* __restrict__ WoT){
  const float* in; u16* out; int ldin;
  switch (blockIdx.z){
    case 0:  in = Wq;         out = WqT; ldin = 1024; break;
    case 1:  in = Wkv;        out = WkT; ldin = 2048; break;
    case 2:  in = Wkv + 1024; out = WvT; ldin = 2048; break;
    default: in = Wout;       out = WoT; ldin = 1024; break;
  }
  float scl = (blockIdx.z == 0) ? 1.44269504f : 1.0f;
  __shared__ float tile[64][65];
  int t = threadIdx.x;
  int tr = blockIdx.y * 64, tc = blockIdx.x * 64;
  int r0 = t >> 4, c0 = (t & 15) * 4;
#pragma unroll
  for (int i = 0; i < 4; ++i){
    int r = r0 + i * 16;
    const float4 val = *(const float4*)&in[(size_t)(tr + r) * ldin + tc + c0];
    tile[r][c0] = val.x; tile[r][c0+1] = val.y; tile[r][c0+2] = val.z; tile[r][c0+3] = val.w;
  }
  __syncthreads();
#pragma unroll
  for (int i = 0; i < 4; ++i){
    int n = r0 + i * 16;
    u16x4 o4;
    o4.x = f2bf(tile[c0+0][n] * scl); o4.y = f2bf(tile[c0+1][n] * scl);
    o4.z = f2bf(tile[c0+2][n] * scl); o4.w = f2bf(tile[c0+3][n] * scl);
    *(u16x4*)&out[(size_t)(tc + n) * 1024 + tr + c0] = o4;
  }
}

// ---------------- layernorm + bf16 cast, one row per block ----------------
__global__ __launch_bounds__(256) void ln_cast(const float* __restrict__ x, const float* __restrict__ xa,
                                               const float* __restrict__ w, const float* __restrict__ bb,
                                               u16* __restrict__ xn, u16* __restrict__ xan){
  int row = blockIdx.x;
  const float* src; u16* dst;
  if (row < 4096){ src = x + (size_t)row * 1024; dst = xn + (size_t)row * 1024; }
  else { src = xa + (size_t)(row - 4096) * 1024; dst = xan + (size_t)(row - 4096) * 1024; }
  int t = threadIdx.x;
  float4 v = ((const float4*)src)[t];
  float s = v.x + v.y + v.z + v.w;
  float ss = v.x*v.x + v.y*v.y + v.z*v.z + v.w*v.w;
#pragma unroll
  for (int o = 32; o > 0; o >>= 1){ s += __shfl_down(s, o); ss += __shfl_down(ss, o); }
  __shared__ float red[8];
  int wv = t >> 6;
  if ((t & 63) == 0){ red[wv] = s; red[wv + 4] = ss; }
  __syncthreads();
  if (t == 0){
    red[0] = red[0] + red[1] + red[2] + red[3];
    red[4] = red[4] + red[5] + red[6] + red[7];
  }
  __syncthreads();
  float mu = red[0] * (1.0f/1024.0f);
  float var = red[4] * (1.0f/1024.0f) - mu*mu;
  float rstd = rsqrtf(var + 1e-5f);
  float4 wv4 = ((const float4*)w)[t];
  float4 bv4 = ((const float4*)bb)[t];
  u16x4 o4;
  o4.x = f2bf((v.x - mu) * rstd * wv4.x + bv4.x);
  o4.y = f2bf((v.y - mu) * rstd * wv4.y + bv4.y);
  o4.z = f2bf((v.z - mu) * rstd * wv4.z + bv4.z);
  o4.w = f2bf((v.w - mu) * rstd * wv4.w + bv4.w);
  ((u16x4*)dst)[t] = o4;
}

// ---------------- BMx256 GEMM, BK=64, 8 waves, dbuf, counted vmcnt (R8/R11-proven) ----
// Epilogue change (R17): transposed quads pack r=0..3 (consecutive tokens) into
// one u16x4 store -> 4x fewer store instrs, 4x smaller cacheline footprint.
template<int BM, int NQ, int TMASK, typename OutT>
__global__ __launch_bounds__(512, 2) void gemm256(
    const u16* __restrict__ A0, const u16* __restrict__ A1,
    const u16* __restrict__ A2, const u16* __restrict__ A3,
    const u16* __restrict__ B0, const u16* __restrict__ B1,
    const u16* __restrict__ B2, const u16* __restrict__ B3,
    OutT* __restrict__ C0, OutT* __restrict__ C1,
    OutT* __restrict__ C2, OutT* __restrict__ C3){
  constexpr int AI = BM / 64;
  constexpr int FI = BM / 32;
  constexpr int MT = (NQ == 4) ? 16 : 64;
  __shared__ u16 SA[2][BM * 64];
  __shared__ u16 SB[2][16384];
  int tid = threadIdx.x, lane = tid & 63, wave = tid >> 6;
  int g = lane >> 4, r15 = lane & 15;
  int id = blockIdx.x;
  int r8 = id & 7, k = id >> 3;
  int gm = (k >> 2) * 8 + r8;
  int ntile = k & 3;
  int quad = gm / MT;
  int mbase = (gm % MT) * BM, nbase = ntile * 256;
  const u16* A = quad==0?A0:quad==1?A1:quad==2?A2:A3;
  const u16* B = quad==0?B0:quad==1?B1:quad==2?B2:B3;
  OutT* C      = quad==0?C0:quad==1?C1:quad==2?C2:C3;
  int wr = wave >> 2, wc = wave & 3;
  int rsub = lane >> 3;
  int slo  = (lane & 7) ^ ((lane >> 3) & 7);
  int sw8  = (r15 & 7) << 3;
  f32x4 acc[FI][4] = {};

#define STG(kt, b) { \
  int ko = (kt) * 64; \
  _Pragma("unroll") \
  for (int i = 0; i < AI; ++i){ \
    int row = i*64 + wave*8 + rsub; \
    load_lds16(A + (size_t)(mbase + row)*1024 + ko + slo*8, &SA[b][(i*512 + wave*64)*8]); \
  } \
  _Pragma("unroll") \
  for (int i = 0; i < 4; ++i){ \
    int row = i*64 + wave*8 + rsub; \
    load_lds16(B + (size_t)(nbase + row)*1024 + ko + slo*8, &SB[b][(i*512 + wave*64)*8]); \
  } }

  STG(0, 0);
  for (int t = 0; t < 16; ++t){
    int b = t & 1;
    if (t < 15){
      STG(t + 1, b ^ 1);
      if constexpr (AI == 4) asm volatile("s_waitcnt vmcnt(8)" ::: "memory");
      else                   asm volatile("s_waitcnt vmcnt(6)" ::: "memory");
    } else {
      asm volatile("s_waitcnt vmcnt(0)" ::: "memory");
    }
    __builtin_amdgcn_s_barrier();
    __builtin_amdgcn_sched_barrier(0);
    const u16* Al = &SA[b][0];
    const u16* Bl = &SB[b][0];
#pragma unroll
    for (int ks = 0; ks < 2; ++ks){
      bf16x8 af[FI], bfr[4];
#pragma unroll
      for (int fi = 0; fi < FI; ++fi)
        af[fi] = *(const bf16x8*)&Al[(wr*(FI*16) + fi*16 + r15)*64 + ((ks*32 + g*8) ^ sw8)];
#pragma unroll
      for (int fj = 0; fj < 4; ++fj)
        bfr[fj] = *(const bf16x8*)&Bl[(wc*64 + fj*16 + r15)*64 + ((ks*32 + g*8) ^ sw8)];
#pragma unroll
      for (int fi = 0; fi < FI; ++fi)
#pragma unroll
        for (int fj = 0; fj < 4; ++fj)
          acc[fi][fj] = __builtin_amdgcn_mfma_f32_16x16x32_bf16(af[fi], bfr[fj], acc[fi][fj], 0, 0, 0);
    }
    __builtin_amdgcn_s_barrier();
  }
#undef STG

  bool tr = (TMASK >> quad) & 1;
#pragma unroll
  for (int fi = 0; fi < FI; ++fi)
#pragma unroll
    for (int fj = 0; fj < 4; ++fj){
      int colb = nbase + wc*64 + fj*16 + r15;
      int row0 = mbase + wr*(FI*16) + fi*16 + g*4;
      if constexpr (TMASK != 0){
        if (tr){
          // vT[bh][d][token]: r = consecutive tokens -> one packed 8B store
          int bb = row0 >> 10, token = row0 & 1023;   // rows 0..3 same bb (mbase % 256 == 0)
          int hh = colb >> 6, dd = colb & 63;
          u16x4 o;
          o.x = f2bf(acc[fi][fj][0]); o.y = f2bf(acc[fi][fj][1]);
          o.z = f2bf(acc[fi][fj][2]); o.w = f2bf(acc[fi][fj][3]);
          *(u16x4*)((u16*)C + ((size_t)((bb << 4) + hh) * 64 + dd) * 1024 + token) = o;
          continue;
        }
      }
#pragma unroll
      for (int r = 0; r < 4; ++r)
        storeC(&C[(size_t)(row0 + r) * 1024 + colb], acc[fi][fj][r]);
    }
}

// ---------------- flash attention, both directions (R16-passing, byte-identical) ----
// 1D grid 2048, XCD-bijective decode. 256 thr, 4 waves x 16 q-rows.
// DS-pipe diet: K/VT staged via global_load_lds (pre-swizzled source, linear
// dest), LDS double-buffered with counted vmcnt(4) across raw barriers (gemm's
// proven protocol). l-reduction deferred to epilogue. No-max exp2 softmax.
#define SW(row, col) ((row) * 64 + ((col) ^ (((row) & 7) << 3)))

__device__ __forceinline__ void exchP(const f32x4& s0, const f32x4& s1,
                                      const f32x4& s2, const f32x4& s3,
                                      bool gh, bool g0, bf16x8& pf0, bf16x8& pf1){
  u32 pk00 = cvtpk(s0[0], s0[1]), pk01 = cvtpk(s0[2], s0[3]);
  u32 pk10 = cvtpk(s1[0], s1[1]), pk11 = cvtpk(s1[2], s1[3]);
  u32 pk20 = cvtpk(s2[0], s2[1]), pk21 = cvtpk(s2[2], s2[3]);
  u32 pk30 = cvtpk(s3[0], s3[1]), pk31 = cvtpk(s3[2], s3[3]);
  u32 c0 = gh ? pk10 : pk00, c1 = gh ? pk11 : pk01;
  u32 d0 = gh ? pk00 : pk10, d1 = gh ? pk01 : pk11;
  u32 s1a = __shfl_xor((int)c0, 16), s1b = __shfl_xor((int)c1, 16);
  u32 s2a = __shfl_xor((int)d0, 32), s2b = __shfl_xor((int)d1, 32);
  u32 s3a = __shfl_xor((int)d0, 48), s3b = __shfl_xor((int)d1, 48);
  union UB { u32 w[4]; bf16x8 v; } ub0, ub1;
  ub0.w[0] = gh ? (g0 ? s1a : s2a) : (g0 ? s3a : c0);
  ub0.w[1] = gh ? (g0 ? s1b : s2b) : (g0 ? s3b : c1);
  ub0.w[2] = gh ? (g0 ? c0 : s3a) : (g0 ? s2a : s1a);
  ub0.w[3] = gh ? (g0 ? c1 : s3b) : (g0 ? s2b : s1b);
  u32 e0 = gh ? pk30 : pk20, e1 = gh ? pk31 : pk21;
  u32 f0 = gh ? pk20 : pk30, f1 = gh ? pk21 : pk31;
  u32 t1a = __shfl_xor((int)e0, 16), t1b = __shfl_xor((int)e1, 16);
  u32 t2a = __shfl_xor((int)f0, 32), t2b = __shfl_xor((int)f1, 32);
  u32 t3a = __shfl_xor((int)f0, 48), t3b = __shfl_xor((int)f1, 48);
  ub1.w[0] = gh ? (g0 ? t1a : t2a) : (g0 ? t3a : e0);
  ub1.w[1] = gh ? (g0 ? t1b : t2b) : (g0 ? t3b : e1);
  ub1.w[2] = gh ? (g0 ? e0 : t3a) : (g0 ? t2a : t1a);
  ub1.w[3] = gh ? (g0 ? e1 : t3b) : (g0 ? t2b : t1b);
  pf0 = ub0.v; pf1 = ub1.v;
}

#define MFMA16(a, b, c) __builtin_amdgcn_mfma_f32_16x16x32_bf16(a, b, c, 0, 0, 0)

__global__ __launch_bounds__(256) void flash(const u16* __restrict__ qg, const u16* __restrict__ vTg,
                                             const u16* __restrict__ kag, const u16* __restrict__ vaTg,
                                             u16* __restrict__ xu, u16* __restrict__ xau){
  __shared__ u16 Ks[2][4096], VTs[2][4096];
  int tid = threadIdx.x, lane = tid & 63, wave = tid >> 6, g = lane >> 4, r15 = lane & 15;
  int b = blockIdx.x;
  int xcd = b & 7, idx = b >> 3;
  int qt = idx & 15;
  int pair = xcd * 16 + (idx >> 4);
  int bh = pair & 63, dir = pair >> 6;
  size_t tokbase = ((size_t)(bh >> 4)) * 1048576 + (size_t)(bh & 15) * 64;
  size_t vtbase  = (size_t)bh << 16;
  const u16 *Q, *K, *VT; u16* O;
  if (dir == 0){ Q = qg + tokbase;  K = kag + tokbase; VT = vaTg + vtbase; O = xu  + tokbase; }
  else         { Q = kag + tokbase; K = qg  + tokbase; VT = vTg  + vtbase; O = xau + tokbase; }
  Q += (size_t)qt * 64 * 1024;
  O += (size_t)qt * 64 * 1024;

  int wq = wave * 16;
  bf16x8 qf0 = *(const bf16x8*)&Q[(size_t)(wq + r15) * 1024 + g*8];
  bf16x8 qf1 = *(const bf16x8*)&Q[(size_t)(wq + r15) * 1024 + 32 + g*8];

  // staging source (pre-swizzled): row = wave*8 + i*32 + rl, chunk = (lane&7)^rl
  // (row&7 == rl since wave*8 and i*32 are 0 mod 8); LDS dest linear.
  int rl = lane >> 3;
  int ch = (lane & 7) ^ rl;
  const u16* Kb = K  + (size_t)(wave*8 + rl) * 1024 + ch*8;
  const u16* Vb = VT + (size_t)(wave*8 + rl) * 1024 + ch*8;

#define FSTG(j, buf) { \
  load_lds16(Kb + (size_t)(j)*65536,                 &Ks [buf][(wave*8)*64]); \
  load_lds16(Kb + (size_t)(j)*65536 + 32*1024,       &Ks [buf][(wave*8 + 32)*64]); \
  load_lds16(Vb + (j)*64,                            &VTs[buf][(wave*8)*64]); \
  load_lds16(Vb + (j)*64 + (size_t)32*1024,          &VTs[buf][(wave*8 + 32)*64]); \
}

  float pl = 0.0f;                      // per-lane l partial; cross-g reduce deferred
  f32x4 acc[4] = {};
  bool gh = g >= 2, g0 = g & 1;
  const f32x4 zinit = {-32.f, -32.f, -32.f, -32.f};

  FSTG(0, 0);
  for (int j = 0; j < 16; ++j){
    int buf = j & 1;
    if (j < 15){
      FSTG(j + 1, buf ^ 1);             // writes buf read LAST iter (safe past its barrier)
      asm volatile("s_waitcnt vmcnt(4)" ::: "memory");  // tile j landed; j+1 in flight
    } else {
      asm volatile("s_waitcnt vmcnt(0)" ::: "memory");
    }
    __builtin_amdgcn_s_barrier();       // tile j visible to all waves
    __builtin_amdgcn_sched_barrier(0);
    const u16* kb = &Ks[buf][0];
    const u16* vb = &VTs[buf][0];

    // S' - 32 = K Q^T + (-32): rows kv = 16*kvi + 4g + reg, col q = r15
    f32x4 sf[4];
    __builtin_amdgcn_s_setprio(1);
#pragma unroll
    for (int kvi = 0; kvi < 4; ++kvi){
      bf16x8 kf0 = *(const bf16x8*)&kb[SW(kvi*16 + r15, g*8)];
      bf16x8 kf1 = *(const bf16x8*)&kb[SW(kvi*16 + r15, 32 + g*8)];
      f32x4 z = MFMA16(kf0, qf0, zinit);
      z = MFMA16(kf1, qf1, z);
      sf[kvi] = z;
    }
    __builtin_amdgcn_s_setprio(0);

    // P = exp2(S' - 32); per-lane partial sum only
#pragma unroll
    for (int kvi = 0; kvi < 4; ++kvi)
#pragma unroll
      for (int r = 0; r < 4; ++r){
        float p = __builtin_amdgcn_exp2f(sf[kvi][r]);
        sf[kvi][r] = p; pl += p;
      }

    bf16x8 pf0, pf1;
    exchP(sf[0], sf[1], sf[2], sf[3], gh, g0, pf0, pf1);

    // PV: out^T[d][q] += V^T[d][kv] * P^T
    __builtin_amdgcn_s_setprio(1);
#pragma unroll
    for (int nb = 0; nb < 4; ++nb){
      bf16x8 vf0 = *(const bf16x8*)&vb[SW(nb*16 + r15, g*8)];
      acc[nb] = MFMA16(vf0, pf0, acc[nb]);
    }
#pragma unroll
    for (int nb = 0; nb < 4; ++nb){
      bf16x8 vf1 = *(const bf16x8*)&vb[SW(nb*16 + r15, 32 + g*8)];
      acc[nb] = MFMA16(vf1, pf1, acc[nb]);
    }
    __builtin_amdgcn_s_setprio(0);
    __builtin_amdgcn_s_barrier();       // reads of buf done -> next iter may stage into buf^1
  }
#undef FSTG

  // epilogue: one cross-g reduce for l, then normalize + store
  pl += __shfl_xor(pl, 16);
  pl += __shfl_xor(pl, 32);
  float inv = 1.0f / pl;
  size_t orow = (size_t)(wq + r15) * 1024;
#pragma unroll
  for (int nb = 0; nb < 4; ++nb){
    u16x4 o;
    o.x = f2bf(acc[nb][0] * inv);
    o.y = f2bf(acc[nb][1] * inv);
    o.z = f2bf(acc[nb][2] * inv);
    o.w = f2bf(acc[nb][3] * inv);
    *(u16x4*)&O[orow + nb*16 + g*4] = o;
  }
}

extern "C" void kernel_launch(void* const* d_in, const int* in_sizes, int n_in,
                              void* d_out, int out_size, void* d_ws, size_t ws_size,
                              hipStream_t stream){
  const float* x    = (const float*)d_in[0];
  const float* xa   = (const float*)d_in[1];
  const float* lnw  = (const float*)d_in[2];
  const float* lnb  = (const float*)d_in[3];
  const float* Wq   = (const float*)d_in[4];
  const float* Wkv  = (const float*)d_in[5];
  const float* Wout = (const float*)d_in[6];
  float* out = (float*)d_out;
  char* ws = (char*)d_ws;
  const size_t MB = 1ull << 20;
  u16* xn  = (u16*)(ws);
  u16* xan = (u16*)(ws + 8*MB);
  u16* q   = (u16*)(ws + 16*MB);
  u16* vT  = (u16*)(ws + 24*MB);
  u16* ka  = (u16*)(ws + 32*MB);
  u16* vaT = (u16*)(ws + 40*MB);
  u16* xu  = (u16*)(ws + 48*MB);   // xu..xau contiguous -> M=8192 out-GEMM
  u16* xau = (u16*)(ws + 56*MB);
  u16* WqT = (u16*)(ws + 64*MB);
  u16* WkT = (u16*)(ws + 66*MB);
  u16* WvT = (u16*)(ws + 68*MB);
  u16* WoT = (u16*)(ws + 70*MB);
  dim3 blk(256);
  transpose_all<<<dim3(16,16,4), blk, 0, stream>>>(Wq, Wkv, Wout, WqT, WkT, WvT, WoT);
  ln_cast<<<8192, blk, 0, stream>>>(x, xa, lnw, lnb, xn, xan);
  // proj: quads 0:q, 1:vT(tr), 2:ka, 3:vaT(tr). 1-D 256 blocks, XCD-grouped.
  gemm256<256, 4, 0xA, u16><<<dim3(256), dim3(512), 0, stream>>>(
      xn, xn, xan, xan, WqT, WvT, WkT, WvT, q, vT, ka, vaT);
  flash<<<dim3(2048), blk, 0, stream>>>(q, vT, ka, vaT, xu, xau);
  // out: single M=8192 GEMM (xu||xau) @ WoT -> (out0||out1) f32. 256 blocks.
  gemm256<128, 1, 0, float><<<dim3(256), dim3(512), 0, stream>>>(
      xu, xu, xu, xu, WoT, WoT, WoT, WoT, out, out, out, out);
}